// Round 3
// baseline (716.059 us; speedup 1.0000x reference)
//
#include <hip/hip_runtime.h>
#include <math.h>

// Problem constants (from reference setup_inputs)
#define BB 32
#define SS 2048
#define NN 16
#define DD 128
#define ND (NN * DD)      // 2048 floats per (b, s) slice
#define ND4 (ND / 4)      // 512 float4 per slice
#define HH 64             // hidden dim

#define CS 64             // s-chunk per block in reduce kernel
#define NCHUNK (SS / CS)  // 32 chunks

// ws layout: [16 MiB, 24 MiB) partial sums (BB*NCHUNK*ND floats = 8 MiB)
#define PARTIAL_OFF_BYTES (16u * 1024u * 1024u)

// ---------------------------------------------------------------------------
// Kernel A: per-(b, s-chunk) partial sums, plain float4 stores (no init, no
// atomics). grid = BB*NCHUNK = 1024 blocks, 256 threads. Each thread owns 2
// float4 columns and streams CS=64 s-slices (coalesced dwordx4). This is the
// mandatory 512 MiB HBM read — the whole problem's roofline.
// ---------------------------------------------------------------------------
__global__ __launch_bounds__(256) void partial_sum_kernel(
    const float* __restrict__ x, float4* __restrict__ partial) {
  const int blk   = blockIdx.x;          // b*32 + chunk
  const int b     = blk >> 5;
  const int chunk = blk & 31;
  const int t     = threadIdx.x;

  const float4* xb = (const float4*)x +
                     (size_t)b * SS * ND4 + (size_t)chunk * CS * ND4;

  const int c0 = t;
  const int c1 = t + 256;

  float4 a0 = make_float4(0.f, 0.f, 0.f, 0.f);
  float4 a1 = make_float4(0.f, 0.f, 0.f, 0.f);

#pragma unroll 8
  for (int s = 0; s < CS; ++s) {
    const float4 v0 = xb[(size_t)s * ND4 + c0];
    const float4 v1 = xb[(size_t)s * ND4 + c1];
    a0.x += v0.x; a0.y += v0.y; a0.z += v0.z; a0.w += v0.w;
    a1.x += v1.x; a1.y += v1.y; a1.z += v1.z; a1.w += v1.w;
  }

  float4* p = partial + (size_t)blk * ND4;
  p[c0] = a0;
  p[c1] = a1;
}

// ---------------------------------------------------------------------------
// Kernel B (fused finalize + pair MLP): 128 blocks = 4 per batch, 256 thr.
// Phase 1: block reduces the 32 chunk-partials of its batch into an 8 KB LDS
//          mean slice (256 KB L2/L3-resident reads per block).
// Phase 2: each of the 4 waves walks pairs p = waveInBatch + 16*t (120 pairs
//          per batch across 16 waves). Lane k = hidden unit k: mean reads are
//          LDS same-address broadcasts (free), W1 column loads lane-coalesced
//          from L1/L2. Exact-erf GELU, 64-lane shuffle reduce, lane 0 writes
//          sigmoid to both mirrored cells. Wave 0 of each batch zeroes the
//          diagonal (out is poisoned 0xAA each call).
// ---------------------------------------------------------------------------
__global__ __launch_bounds__(256) void fused_mean_pair_kernel(
    const float4* __restrict__ partial, const float* __restrict__ W1,
    const float* __restrict__ b1, const float* __restrict__ W2,
    const float* __restrict__ b2, float* __restrict__ out) {
  __shared__ float smean[ND];  // 8 KB

  const int b   = blockIdx.x >> 2;   // batch
  const int sub = blockIdx.x & 3;    // sub-block within batch
  const int t   = threadIdx.x;

  // ---- Phase 1: mean for batch b into LDS ----
  const float4* pb = partial + (size_t)b * NCHUNK * ND4;
  float4 a0 = make_float4(0.f, 0.f, 0.f, 0.f);
  float4 a1 = make_float4(0.f, 0.f, 0.f, 0.f);
#pragma unroll
  for (int ch = 0; ch < NCHUNK; ++ch) {
    const float4 v0 = pb[(size_t)ch * ND4 + t];
    const float4 v1 = pb[(size_t)ch * ND4 + t + 256];
    a0.x += v0.x; a0.y += v0.y; a0.z += v0.z; a0.w += v0.w;
    a1.x += v1.x; a1.y += v1.y; a1.z += v1.z; a1.w += v1.w;
  }
  const float inv = 1.0f / (float)SS;
  a0.x *= inv; a0.y *= inv; a0.z *= inv; a0.w *= inv;
  a1.x *= inv; a1.y *= inv; a1.z *= inv; a1.w *= inv;
  ((float4*)smean)[t]       = a0;
  ((float4*)smean)[t + 256] = a1;
  __syncthreads();

  // ---- Phase 2: pair MLP ----
  const int wave = t >> 6;           // 0..3
  const int lane = t & 63;
  const int wib  = sub * 4 + wave;   // wave index within batch, 0..15

  float* ob = out + (size_t)b * NN * NN;
  if (wib == 0 && lane < NN) ob[lane * NN + lane] = 0.0f;

  for (int p = wib; p < 120; p += 16) {
    // decode triangular index p -> (i, j), i<j (wave-uniform)
    int k = p, i = 0;
    while (k >= 15 - i) { k -= 15 - i; ++i; }
    const int j = i + 1 + k;

    const float* mi = smean + i * DD;
    const float* mj = smean + j * DD;

    float acc = b1[lane];
#pragma unroll 8
    for (int d = 0; d < DD; ++d) {
      acc = fmaf(mi[d], W1[d * HH + lane], acc);
      acc = fmaf(mj[d], W1[(DD + d) * HH + lane], acc);
    }

    // exact GELU: 0.5*x*(1+erf(x/sqrt(2)))
    const float hk = 0.5f * acc * (1.0f + erff(acc * 0.7071067811865476f));

    float v = hk * W2[lane];
#pragma unroll
    for (int off = 32; off > 0; off >>= 1) v += __shfl_down(v, off, 64);

    if (lane == 0) {
      const float s = 1.0f / (1.0f + expf(-(v + b2[0])));
      ob[i * NN + j] = s;
      ob[j * NN + i] = s;
    }
  }
}

extern "C" void kernel_launch(void* const* d_in, const int* in_sizes, int n_in,
                              void* d_out, int out_size, void* d_ws,
                              size_t ws_size, hipStream_t stream) {
  const float* x  = (const float*)d_in[0];  // [B,S,N,D]
  const float* W1 = (const float*)d_in[1];  // [2D,H]
  const float* b1 = (const float*)d_in[2];  // [H]
  const float* W2 = (const float*)d_in[3];  // [H,1]
  const float* b2 = (const float*)d_in[4];  // [1]
  float* out = (float*)d_out;               // [B,N,N] = 8192 floats

  float4* partial = (float4*)((char*)d_ws + PARTIAL_OFF_BYTES);  // 8 MiB

  partial_sum_kernel<<<BB * NCHUNK, 256, 0, stream>>>(x, partial);
  fused_mean_pair_kernel<<<128, 256, 0, stream>>>(partial, W1, b1, W2, b2,
                                                  out);
}